// Round 1
// baseline (84.229 us; speedup 1.0000x reference)
//
#include <hip/hip_runtime.h>

#define N_REAL   12
#define BATCH    4
#define CH       3
#define HH       256
#define WW       256
#define KK       4
#define TILE     32
#define HALO     (TILE + KK - 1)   /* 35 */
#define NTHR     256

__device__ __forceinline__ float sigmoidf(float x) {
    // sigmoid(x) = 1 / (1 + exp(-x));  exp(-x) = 2^(-x*log2(e))
    float e = __builtin_amdgcn_exp2f(x * -1.44269504088896340736f);
    return __builtin_amdgcn_rcpf(1.0f + e);
}

__global__ __launch_bounds__(NTHR, 2)
void reverb_fused(const float* __restrict__ states,
                  const float* __restrict__ weights,
                  const float* __restrict__ bias,
                  const int*   __restrict__ esrc,
                  const int*   __restrict__ edst,
                  float*       __restrict__ out,
                  int E)
{
    __shared__ float sIn[CH][HALO][HALO];          // 14.7 KB, stride 35 -> 2-way (free)
    __shared__ float sW[CH][CH][KK][KK];           // 576 B
    __shared__ float sB[CH];

    const int v    = blockIdx.z;                   // destination node 0..11
    const int b    = blockIdx.y;                   // batch
    const int tile = blockIdx.x;                   // 0..63
    const int oy0  = (tile / (WW / TILE)) * TILE;
    const int ox0  = (tile % (WW / TILE)) * TILE;

    const int tid = threadIdx.x;
    const int y   = tid >> 3;                      // 0..31   output row in tile
    const int x0  = (tid & 7) << 2;                // 0,4,...,28  4 consecutive pixels

    float acc[CH][4];
    #pragma unroll
    for (int co = 0; co < CH; ++co)
        #pragma unroll
        for (int p = 0; p < 4; ++p) acc[co][p] = 0.0f;
    float bsum[CH] = {0.0f, 0.0f, 0.0f};
    int   deg = 0;

    for (int e = 0; e < E; ++e) {
        if (edst[e] != v) continue;                // block-uniform branch
        const int u = esrc[e];
        ++deg;

        __syncthreads();                           // protect LDS from prev edge's readers

        // ---- stage haloed input tile (sigmoid applied) ----
        const float* src = states + (((size_t)u * BATCH + b) * CH) * (size_t)(HH * WW);
        for (int idx = tid; idx < CH * HALO * HALO; idx += NTHR) {
            int ci = idx / (HALO * HALO);
            int r  = idx % (HALO * HALO);
            int iy = r / HALO, ix = r % HALO;
            int gy = oy0 + iy - 1;                 // SAME pad: lo=1, hi=2
            int gx = ox0 + ix - 1;
            float val = 0.0f;
            if ((unsigned)gy < (unsigned)HH && (unsigned)gx < (unsigned)WW)
                val = sigmoidf(src[ci * (HH * WW) + gy * WW + gx]);
            ((float*)sIn)[idx] = val;
        }
        // ---- stage weights + bias ----
        for (int idx = tid; idx < CH * CH * KK * KK; idx += NTHR)
            ((float*)sW)[idx] = weights[(size_t)e * (CH * CH * KK * KK) + idx];
        if (tid < CH) sB[tid] = bias[e * CH + tid];
        __syncthreads();

        #pragma unroll
        for (int co = 0; co < CH; ++co) bsum[co] += sB[co];

        // ---- conv accumulate: 3 ci * 4 ky * (7 loads -> 4kx*3co*4p FMAs) ----
        #pragma unroll
        for (int ci = 0; ci < CH; ++ci) {
            #pragma unroll
            for (int ky = 0; ky < KK; ++ky) {
                float vv[7];
                #pragma unroll
                for (int j = 0; j < 7; ++j)
                    vv[j] = sIn[ci][y + ky][x0 + j];
                #pragma unroll
                for (int kx = 0; kx < KK; ++kx) {
                    #pragma unroll
                    for (int co = 0; co < CH; ++co) {
                        float w = sW[co][ci][ky][kx];
                        #pragma unroll
                        for (int p = 0; p < 4; ++p)
                            acc[co][p] = fmaf(w, vv[p + kx], acc[co][p]);
                    }
                }
            }
        }
    }

    const float inv = 1.0f / (float)deg;           // deg = 3 (or 4 for node 0)
    const size_t obase = (((size_t)v * BATCH + b) * CH) * (size_t)(HH * WW);
    #pragma unroll
    for (int co = 0; co < CH; ++co) {
        float4 o;
        o.x = (acc[co][0] + bsum[co]) * inv;
        o.y = (acc[co][1] + bsum[co]) * inv;
        o.z = (acc[co][2] + bsum[co]) * inv;
        o.w = (acc[co][3] + bsum[co]) * inv;
        *(float4*)&out[obase + (size_t)co * (HH * WW) + (size_t)(oy0 + y) * WW + ox0 + x0] = o;
    }
}

extern "C" void kernel_launch(void* const* d_in, const int* in_sizes, int n_in,
                              void* d_out, int out_size, void* d_ws, size_t ws_size,
                              hipStream_t stream)
{
    const float* states  = (const float*)d_in[0];
    const float* weights = (const float*)d_in[1];
    const float* bias    = (const float*)d_in[2];
    const int*   esrc    = (const int*)d_in[3];
    const int*   edst    = (const int*)d_in[4];
    float*       out     = (float*)d_out;
    const int E = in_sizes[3];

    dim3 grid(WW / TILE * (HH / TILE), BATCH, N_REAL);   // 64 x 4 x 12
    reverb_fused<<<grid, NTHR, 0, stream>>>(states, weights, bias, esrc, edst, out, E);
}